// Round 2
// baseline (338.521 us; speedup 1.0000x reference)
//
#include <hip/hip_runtime.h>
#include <hip/hip_bf16.h>
#include <math.h>

#define VOCAB 100000
#define EMB 100
#define HID 100
#define CTX_LEN 60
#define FACT_LEN 20
#define DESC_LEN 60
#define NCHUNK (VOCAB / 16)     // 6250 column chunks of 16
#define GRID 224                // blocks (<= 256 CUs, all co-resident: 96.5KB LDS -> 1 block/CU)
#define BLOCK 320
#define WPB 5                   // waves per block
#define NWAVES (GRID * WPB)     // 1120

// workspace layout (float offsets)
#define WS_BAR   0              // barrier state: cnt @0, gen @16 (memset to 0 pre-launch)
#define WS_FACTS 64             // 6000
#define WS_X     6144           // 6000
#define WS_H0    12288          // 128
#define WS_GI    12416          // 18000 (60 x 300)
#define WS_H     30464          // 6000  (60 x 100)
#define WS_MS    36864          // float2[60][NWAVES] = 134400 floats
#define WS_WBF   262144         // bf16 w_out fragments: short8[NCHUNK*4*64] = 25.6 MB

typedef __attribute__((ext_vector_type(8))) short short8;
typedef __attribute__((ext_vector_type(4))) float f32x4;

static __device__ __forceinline__ unsigned short f2bf(float f) {
    union { float f; unsigned u; } x; x.f = f;
    unsigned r = (x.u + 0x7FFFu + ((x.u >> 16) & 1u)) >> 16;
    return (unsigned short)r;
}

// device-scope sense-style grid barrier; state in ws[0]/ws[16] (zeroed by host memset)
static __device__ __forceinline__ void grid_sync(float* ws) {
    __syncthreads();
    if (threadIdx.x == 0) {
        unsigned* cnt = (unsigned*)ws;
        unsigned* gen = (unsigned*)ws + 16;
        __threadfence();   // release prior global writes (agent scope, cross-XCD)
        unsigned g = __hip_atomic_load(gen, __ATOMIC_RELAXED, __HIP_MEMORY_SCOPE_AGENT);
        unsigned a = __hip_atomic_fetch_add(cnt, 1u, __ATOMIC_ACQ_REL, __HIP_MEMORY_SCOPE_AGENT);
        if (a == GRID - 1) {
            __hip_atomic_store(cnt, 0u, __ATOMIC_RELAXED, __HIP_MEMORY_SCOPE_AGENT);
            __hip_atomic_store(gen, g + 1u, __ATOMIC_RELEASE, __HIP_MEMORY_SCOPE_AGENT);
        } else {
            while (__hip_atomic_load(gen, __ATOMIC_ACQUIRE, __HIP_MEMORY_SCOPE_AGENT) == g)
                __builtin_amdgcn_s_sleep(2);
        }
        __threadfence();   // acquire: invalidate stale L1/L2 before this phase's reads
    }
    __syncthreads();
}

__global__ __launch_bounds__(BLOCK, 1) void mega(
    const int* __restrict__ context, const int* __restrict__ desc,
    const float* __restrict__ emb_ctx, const float* __restrict__ emb_dec,
    const float* __restrict__ w1, const float* __restrict__ b1,
    const float* __restrict__ w_ih, const float* __restrict__ b_ih,
    const float* __restrict__ w_hh, const float* __restrict__ b_hh,
    const float* __restrict__ w_out, const float* __restrict__ b_out,
    float* __restrict__ ws, float* __restrict__ out)
{
    __shared__ __align__(16) float smem[24128];   // 96.5 KB, unioned across phases
    const int b = blockIdx.x, tid = threadIdx.x;
    const int lane = tid & 63, wave = tid >> 6;
    const int q = lane >> 4, n = lane & 15;

    // ================= Phase A: facts encoder + decoder input embeddings + zero out =================
    if (b < 60) {
        int* toks = (int*)smem;
        if (tid < 20) toks[tid] = context[b * 20 + tid];
        __syncthreads();
        if (tid < 100) {
            float ef = tid * (1.f / 99.f);
            float acc = 0.f;
            #pragma unroll
            for (int s = 0; s < 20; s++) {
                float sf = s * (1.f / 19.f);
                float l = 1.f - sf - ef * (1.f - 2.f * sf);
                acc = fmaf(emb_ctx[toks[s] * 100 + tid], l, acc);
            }
            ws[WS_FACTS + b * 100 + tid] = acc;
        }
    } else if (b < 120) {
        int t = b - 60;
        int tok = (t == 0) ? 1 : desc[t - 1];
        if (tid < 100) ws[WS_X + t * 100 + tid] = emb_dec[tok * 100 + tid];
    } else if (b == 120 && tid == 0) {
        out[0] = 0.f;   // d_out is poisoned; phase E atomicAdds into it
    }
    grid_sync(ws);

    // ================= Phase B: h0 (blocks 0..99) + gi_all (blocks 100..159) =================
    if (b < 100) {
        float* red = smem;
        const float* facts = ws + WS_FACTS;
        const float* wr = w1 + b * 6000;
        float p = 0.f;
        for (int k = tid; k < 6000; k += 320) p = fmaf(facts[k], wr[k], p);
        red[tid] = p; __syncthreads();
        if (tid < 64) red[tid] += red[256 + tid];
        __syncthreads();
        for (int st = 128; st > 0; st >>= 1) {
            if (tid < st) red[tid] += red[tid + st];
            __syncthreads();
        }
        if (tid == 0) ws[WS_H0 + b] = red[0] + b1[b];
    } else if (b < 160) {
        int t = b - 100;
        float* xs = smem;
        if (tid < 100) xs[tid] = ws[WS_X + t * 100 + tid];
        __syncthreads();
        if (tid < 300) {
            float p = b_ih[tid];
            const float* wr = w_ih + tid * 100;
            #pragma unroll 4
            for (int k = 0; k < 100; k++) p = fmaf(wr[k], xs[k], p);
            ws[WS_GI + t * 300 + tid] = p;
        }
    }
    grid_sync(ws);

    // ================= Phase C: block 0 = sequential GRU; blocks 1.. = w_out -> bf16 fragment convert =================
    if (b == 0) {
        float* gi_lds = smem;                                   // 18000
        float* H_lds  = smem + 18000;                           // 6000
        unsigned short (*h_bf)[128] = (unsigned short (*)[128])(smem + 24000);
        const int L = lane & 31;
        const int j = wave * 32 + L;
        const bool gruwave = (wave < 4);
        const bool gate_lane = gruwave && (lane < 32) && (j < 100);

        // B fragments: bfr[s][c][kt] = w_hh[s*100 + wave*32 + c*16 + n][kt*32+q*8 .. +8)
        short8 bfr[3][2][4];
        if (gruwave) {
            #pragma unroll
            for (int s = 0; s < 3; s++) {
                #pragma unroll
                for (int c = 0; c < 2; c++) {
                    const int jrow = wave * 32 + c * 16 + n;
                    const float* wr = w_hh + (s * 100 + jrow) * 100;
                    #pragma unroll
                    for (int kt = 0; kt < 4; kt++) {
                        int k0 = kt * 32 + q * 8;
                        float va[8];
                        #pragma unroll
                        for (int jj = 0; jj < 8; jj++) va[jj] = 0.f;
                        if (jrow < 100) {
                            if (k0 + 4 <= 100) {
                                float4 a = *(const float4*)(wr + k0);
                                va[0] = a.x; va[1] = a.y; va[2] = a.z; va[3] = a.w;
                            }
                            if (k0 + 8 <= 100) {
                                float4 a = *(const float4*)(wr + k0 + 4);
                                va[4] = a.x; va[5] = a.y; va[6] = a.z; va[7] = a.w;
                            }
                        }
                        short8 f;
                        #pragma unroll
                        for (int jj = 0; jj < 8; jj++) f[jj] = (short)f2bf(va[jj]);
                        bfr[s][c][kt] = f;
                    }
                }
            }
        }

        // preload gi (60x300) into LDS
        {
            const float4* src = (const float4*)(ws + WS_GI);
            float4* dst = (float4*)gi_lds;
            for (int k = tid; k < 4500; k += 320) dst[k] = src[k];
        }

        float hreg = 0.f, bh0 = 0.f, bh1 = 0.f, bh2 = 0.f;
        if (gate_lane) {
            hreg = ws[WS_H0 + j];
            bh0 = b_hh[j]; bh1 = b_hh[100 + j]; bh2 = b_hh[200 + j];
        }
        if (tid < 128) {
            h_bf[0][tid] = (tid < 100) ? f2bf(ws[WS_H0 + tid]) : (unsigned short)0;
            h_bf[1][tid] = 0;
        }
        __syncthreads();

        const int js = (gruwave && j < 100) ? j : 0;
        for (int t = 0; t < 60; t++) {
            const int rb = t & 1;
            if (gruwave) {
                float gir = gi_lds[t * 300 + js];
                float giz = gi_lds[t * 300 + 100 + js];
                float gin = gi_lds[t * 300 + 200 + js];

                short8 afr[4];
                #pragma unroll
                for (int kt = 0; kt < 4; kt++)
                    afr[kt] = *(const short8*)&h_bf[rb][kt * 32 + q * 8];

                f32x4 acc[3][2];
                #pragma unroll
                for (int s = 0; s < 3; s++) {
                    #pragma unroll
                    for (int c = 0; c < 2; c++) {
                        f32x4 a = {0.f, 0.f, 0.f, 0.f};
                        a = __builtin_amdgcn_mfma_f32_16x16x32_bf16(afr[0], bfr[s][c][0], a, 0, 0, 0);
                        a = __builtin_amdgcn_mfma_f32_16x16x32_bf16(afr[1], bfr[s][c][1], a, 0, 0, 0);
                        a = __builtin_amdgcn_mfma_f32_16x16x32_bf16(afr[2], bfr[s][c][2], a, 0, 0, 0);
                        a = __builtin_amdgcn_mfma_f32_16x16x32_bf16(afr[3], bfr[s][c][3], a, 0, 0, 0);
                        acc[s][c] = a;
                    }
                }

                if (gate_lane) {
                    const int cc = L >> 4;
                    float ghr = (cc ? acc[0][1][0] : acc[0][0][0]) + bh0;
                    float ghz = (cc ? acc[1][1][0] : acc[1][0][0]) + bh1;
                    float ghn = (cc ? acc[2][1][0] : acc[2][0][0]) + bh2;
                    float r = 1.f / (1.f + __expf(-(gir + ghr)));
                    float z = 1.f / (1.f + __expf(-(giz + ghz)));
                    float a2 = fmaf(r, ghn, gin);
                    float tt = __expf(-2.f * fabsf(a2));
                    float nn = copysignf((1.f - tt) / (1.f + tt), a2);
                    hreg = (1.f - z) * nn + z * hreg;
                    h_bf[rb ^ 1][j] = f2bf(hreg);
                    H_lds[t * 100 + j] = hreg;
                }
            }
            __syncthreads();
        }

        // write H once (fenced to other blocks by the next grid_sync)
        {
            const float4* src = (const float4*)H_lds;
            float4* dst = (float4*)(ws + WS_H);
            for (int k = tid; k < 1500; k += 320) dst[k] = src[k];
        }
    } else {
        // converters: w_out (fp32) -> MFMA-ready bf16 short8 fragments, hidden under GRU
        short8* wbf = (short8*)(ws + WS_WBF);
        for (int it = (b - 1) * WPB + wave; it < NCHUNK * 4; it += (GRID - 1) * WPB) {
            int c = it >> 2, kt = it & 3;
            const float* wr = w_out + (c * 16 + n) * 100;
            int k0 = kt * 32 + q * 8;
            float va[8];
            #pragma unroll
            for (int jj = 0; jj < 8; jj++) va[jj] = 0.f;
            if (k0 + 4 <= 100) {
                float4 a = *(const float4*)(wr + k0);
                va[0] = a.x; va[1] = a.y; va[2] = a.z; va[3] = a.w;
            }
            if (k0 + 8 <= 100) {
                float4 a = *(const float4*)(wr + k0 + 4);
                va[4] = a.x; va[5] = a.y; va[6] = a.z; va[7] = a.w;
            }
            short8 f;
            #pragma unroll
            for (int jj = 0; jj < 8; jj++) f[jj] = (short)f2bf(va[jj]);
            wbf[(c * 4 + kt) * 64 + lane] = f;
        }
    }
    grid_sync(ws);

    // ================= Phase D: logits GEMM + online softmax partials (all blocks) =================
    {
        const float* H = ws + WS_H;
        float* ms = ws + WS_MS;
        const short8* wbf = (const short8*)(ws + WS_WBF);
        const int gw = b * WPB + wave;
        const int k_base = q * 8;

        short8 afr[4][4];
        #pragma unroll
        for (int mt = 0; mt < 4; mt++) {
            int m = mt * 16 + n;
            #pragma unroll
            for (int kt = 0; kt < 4; kt++) {
                int k0 = kt * 32 + k_base;
                float va[8];
                #pragma unroll
                for (int jj = 0; jj < 8; jj++) va[jj] = 0.f;
                if (m < 60) {
                    if (k0 + 4 <= 100) {
                        float4 a = *(const float4*)(H + m * 100 + k0);
                        va[0] = a.x; va[1] = a.y; va[2] = a.z; va[3] = a.w;
                    }
                    if (k0 + 8 <= 100) {
                        float4 a = *(const float4*)(H + m * 100 + k0 + 4);
                        va[4] = a.x; va[5] = a.y; va[6] = a.z; va[7] = a.w;
                    }
                }
                short8 f;
                #pragma unroll
                for (int jj = 0; jj < 8; jj++) f[jj] = (short)f2bf(va[jj]);
                afr[mt][kt] = f;
            }
        }

        float mS[16], sS[16];
        #pragma unroll
        for (int i = 0; i < 16; i++) { mS[i] = -3.0e38f; sS[i] = 0.f; }

        for (int c = gw; c < NCHUNK; c += NWAVES) {
            int row = c * 16 + n;
            short8 bw0 = wbf[(c * 4 + 0) * 64 + lane];
            short8 bw1 = wbf[(c * 4 + 1) * 64 + lane];
            short8 bw2 = wbf[(c * 4 + 2) * 64 + lane];
            short8 bw3 = wbf[(c * 4 + 3) * 64 + lane];
            float bo = b_out[row];
            #pragma unroll
            for (int mt = 0; mt < 4; mt++) {
                f32x4 acc = {0.f, 0.f, 0.f, 0.f};
                acc = __builtin_amdgcn_mfma_f32_16x16x32_bf16(afr[mt][0], bw0, acc, 0, 0, 0);
                acc = __builtin_amdgcn_mfma_f32_16x16x32_bf16(afr[mt][1], bw1, acc, 0, 0, 0);
                acc = __builtin_amdgcn_mfma_f32_16x16x32_bf16(afr[mt][2], bw2, acc, 0, 0, 0);
                acc = __builtin_amdgcn_mfma_f32_16x16x32_bf16(afr[mt][3], bw3, acc, 0, 0, 0);
                #pragma unroll
                for (int reg = 0; reg < 4; reg++) {
                    float x = acc[reg] + bo;
                    int i = mt * 4 + reg;
                    float mo = mS[i];
                    float mn = fmaxf(mo, x);
                    sS[i] = sS[i] * __expf(mo - mn) + __expf(x - mn);
                    mS[i] = mn;
                }
            }
        }

        #pragma unroll
        for (int i = 0; i < 16; i++) {
            float m = mS[i], s = sS[i];
            #pragma unroll
            for (int off = 1; off < 16; off <<= 1) {
                float m2 = __shfl_xor(m, off);
                float s2 = __shfl_xor(s, off);
                float mn = fmaxf(m, m2);
                s = s * __expf(m - mn) + s2 * __expf(m2 - mn);
                m = mn;
            }
            mS[i] = m; sS[i] = s;
        }
        if (n == 0) {
            #pragma unroll
            for (int mt = 0; mt < 4; mt++) {
                #pragma unroll
                for (int reg = 0; reg < 4; reg++) {
                    int t = mt * 16 + q * 4 + reg;
                    int i = mt * 4 + reg;
                    if (t < 60) {
                        float2 val; val.x = mS[i]; val.y = sS[i];
                        ((float2*)ms)[t * NWAVES + gw] = val;
                    }
                }
            }
        }
    }
    grid_sync(ws);

    // ================= Phase E: combine partials per t, add -logit[tok], accumulate loss =================
    if (b < 60) {
        const int t = b;
        float* sm  = smem;
        float* ssm = smem + 320;
        float* sd  = smem + 640;
        const float2* msp = (const float2*)(ws + WS_MS);
        float m = -3.0e38f, s = 0.f;
        if (tid < 256) {
            for (int i = tid; i < NWAVES; i += 256) {
                float2 p2 = msp[t * NWAVES + i];
                float mn = fmaxf(m, p2.x);
                s = s * __expf(m - mn) + p2.y * __expf(p2.x - mn);
                m = mn;
            }
            sm[tid] = m; ssm[tid] = s;
        }
        __syncthreads();
        for (int st = 128; st > 0; st >>= 1) {
            if (tid < st) {
                float mo = sm[tid], so = ssm[tid];
                float m2 = sm[tid + st], s2 = ssm[tid + st];
                float mn = fmaxf(mo, m2);
                sm[tid] = mn;
                ssm[tid] = so * __expf(mo - mn) + s2 * __expf(m2 - mn);
            }
            __syncthreads();
        }
        int tok = desc[t];
        float p = 0.f;
        if (tid < 100) p = ws[WS_H + t * 100 + tid] * w_out[tok * 100 + tid];
        if (tid < 256) sd[tid] = p;
        __syncthreads();
        for (int st = 128; st > 0; st >>= 1) {
            if (tid < st) sd[tid] += sd[tid + st];
            __syncthreads();
        }
        if (tid == 0) {
            float logit = sd[0] + b_out[tok];
            atomicAdd(out, sm[0] + logf(ssm[0]) - logit);
        }
    }
}

extern "C" void kernel_launch(void* const* d_in, const int* in_sizes, int n_in,
                              void* d_out, int out_size, void* d_ws, size_t ws_size,
                              hipStream_t stream) {
    const int*   context = (const int*)d_in[0];
    // d_in[1] = fact_lengths (unused by reference)
    const int*   desc    = (const int*)d_in[2];
    const float* emb_ctx = (const float*)d_in[3];
    const float* emb_dec = (const float*)d_in[4];
    const float* w1      = (const float*)d_in[5];
    const float* b1      = (const float*)d_in[6];
    const float* w_ih    = (const float*)d_in[7];
    const float* w_hh    = (const float*)d_in[8];
    const float* b_ih    = (const float*)d_in[9];
    const float* b_hh    = (const float*)d_in[10];
    const float* w_out   = (const float*)d_in[11];
    const float* b_out   = (const float*)d_in[12];
    float* out = (float*)d_out;
    float* ws  = (float*)d_ws;

    // zero the grid-barrier words (ws is poisoned between iterations)
    hipMemsetAsync(ws, 0, 128, stream);
    mega<<<GRID, BLOCK, 0, stream>>>(context, desc, emb_ctx, emb_dec, w1, b1,
                                     w_ih, b_ih, w_hh, b_hh, w_out, b_out, ws, out);
}

// Round 3
// 227.857 us; speedup vs baseline: 1.4857x; 1.4857x over previous
//
#include <hip/hip_runtime.h>
#include <hip/hip_bf16.h>
#include <math.h>

#define VOCAB 100000
#define EMB 100
#define HID 100
#define CTX_LEN 60
#define FACT_LEN 20
#define DESC_LEN 60
#define NCHUNK (VOCAB / 16)     // 6250 column chunks of 16
#define GRID 224                // 1 block/CU (96.5KB LDS), all co-resident on 256 CUs
#define BLOCK 320
#define WPB 5
#define NWAVES (GRID * WPB)     // 1120
#define CPW 6                   // max chunks per wave: ceil(6250/1120)

// ---- flag words (zeroed by 4KB host memset each iteration) ----
#define F_AB   0                // [60]  facts[b] done
#define F_GI   64               // [60]  gi[t] done
#define F_H0   128              // [100] h0[r] done
#define F_H    240              // [1]   H done (GRU finished)
#define F_D    256              // [224] logits partials done
#define F_E    512              // [60]  per-t loss done
#define WS_LOSS 640             // [60]  per-t losses
// ---- data (float offsets) ----
#define WS_FACTS 1024           // 6000
#define WS_H0    7040           // 128
#define WS_GI    7168           // 18000 (60 x 300)
#define WS_H     25216          // 6000  (60 x 100)
#define WS_MS    31232          // float2[60][NWAVES]

typedef __attribute__((ext_vector_type(8))) short short8;
typedef __attribute__((ext_vector_type(4))) float f32x4;

static __device__ __forceinline__ unsigned short f2bf(float f) {
    union { float f; unsigned u; } x; x.f = f;
    unsigned r = (x.u + 0x7FFFu + ((x.u >> 16) & 1u)) >> 16;
    return (unsigned short)r;
}

// release: one relaxed atomic store to our own flag word (no RMW, no line sharing)
static __device__ __forceinline__ void st_flag(float* ws, int idx) {
    __builtin_amdgcn_fence(__ATOMIC_RELEASE, "agent");
    __hip_atomic_store((unsigned*)ws + idx, 1u, __ATOMIC_RELAXED, __HIP_MEMORY_SCOPE_AGENT);
}

// wait for nflags flags starting at base; RELAXED polls + sleep, single ACQUIRE fence on exit
static __device__ __forceinline__ void wait_flags(float* ws, int base, int nflags) {
    const unsigned* f = (const unsigned*)ws + base;
    for (;;) {
        unsigned ok = 1u;
        for (int i = (threadIdx.x & 63); i < nflags; i += 64)
            ok &= __hip_atomic_load(f + i, __ATOMIC_RELAXED, __HIP_MEMORY_SCOPE_AGENT);
        if (__all(ok != 0)) break;
        __builtin_amdgcn_s_sleep(8);
    }
    __builtin_amdgcn_fence(__ATOMIC_ACQUIRE, "agent");
}

__global__ __launch_bounds__(BLOCK, 1) void mega(
    const int* __restrict__ context, const int* __restrict__ desc,
    const float* __restrict__ emb_ctx, const float* __restrict__ emb_dec,
    const float* __restrict__ w1, const float* __restrict__ b1,
    const float* __restrict__ w_ih, const float* __restrict__ b_ih,
    const float* __restrict__ w_hh, const float* __restrict__ b_hh,
    const float* __restrict__ w_out, const float* __restrict__ b_out,
    float* __restrict__ ws, float* __restrict__ out)
{
    __shared__ __align__(16) float smem[24128];   // 96.5 KB, unioned across phases
    const int b = blockIdx.x, tid = threadIdx.x;
    const int lane = tid & 63, wave = tid >> 6;
    const int q = lane >> 4, n = lane & 15;

    // ================= early independent work =================
    if (b < 60) {
        // facts[b] (bit-identical to round-1 k1)
        int* toks = (int*)smem;
        if (tid < 20) toks[tid] = context[b * 20 + tid];
        __syncthreads();
        if (tid < 100) {
            float ef = tid * (1.f / 99.f);
            float acc = 0.f;
            #pragma unroll
            for (int s = 0; s < 20; s++) {
                float sf = s * (1.f / 19.f);
                float l = 1.f - sf - ef * (1.f - 2.f * sf);
                acc = fmaf(emb_ctx[toks[s] * 100 + tid], l, acc);
            }
            ws[WS_FACTS + b * 100 + tid] = acc;
        }
        __syncthreads();
        if (tid == 0) st_flag(ws, F_AB + b);
    } else if (b < 160) {
        // h0 row r (bit-identical to round-1 k2 h0 path)
        wait_flags(ws, F_AB, 60);
        const int r = b - 60;
        float* red = smem;
        const float* facts = ws + WS_FACTS;
        const float* wr = w1 + r * 6000;
        float p = 0.f;
        for (int k = tid; k < 6000; k += 320) p = fmaf(facts[k], wr[k], p);
        red[tid] = p; __syncthreads();
        if (tid < 64) red[tid] += red[256 + tid];
        __syncthreads();
        for (int st = 128; st > 0; st >>= 1) {
            if (tid < st) red[tid] += red[tid + st];
            __syncthreads();
        }
        if (tid == 0) {
            ws[WS_H0 + r] = red[0] + b1[r];
            st_flag(ws, F_H0 + r);
        }
    } else if (b < 220) {
        // gi[t] (bit-identical math to round-1 k2 gi path; embeds x itself)
        const int t = b - 160;
        const int tok = (t == 0) ? 1 : desc[t - 1];
        float* xs = smem;
        if (tid < 100) xs[tid] = emb_dec[tok * 100 + tid];
        __syncthreads();
        if (tid < 300) {
            float p = b_ih[tid];
            const float* wr = w_ih + tid * 100;
            #pragma unroll 4
            for (int k = 0; k < 100; k++) p = fmaf(wr[k], xs[k], p);
            ws[WS_GI + t * 300 + tid] = p;
        }
        __syncthreads();
        if (tid == 0) st_flag(ws, F_GI + t);
    }
    // blocks 220-223: straight to convert

    // ================= GRU (block 0) / register w_out conversion (blocks 1..223) =================
    short8 bw[CPW][4];              // converter fragments; statically indexed only
    const int gw = b * WPB + wave;  // global wave id 0..1119

    if (b != 0) {
        #pragma unroll
        for (int k = 0; k < CPW; k++) {
            int c = gw + k * NWAVES;
            if (c < NCHUNK) {
                const int row = c * 16 + n;
                const float* wr = w_out + row * 100;
                #pragma unroll
                for (int kt = 0; kt < 4; kt++) {
                    int k0 = kt * 32 + q * 8;
                    float va[8];
                    #pragma unroll
                    for (int jj = 0; jj < 8; jj++) va[jj] = 0.f;
                    if (k0 + 4 <= 100) {
                        float4 a = *(const float4*)(wr + k0);
                        va[0] = a.x; va[1] = a.y; va[2] = a.z; va[3] = a.w;
                    }
                    if (k0 + 8 <= 100) {
                        float4 a = *(const float4*)(wr + k0 + 4);
                        va[4] = a.x; va[5] = a.y; va[6] = a.z; va[7] = a.w;
                    }
                    short8 f;
                    #pragma unroll
                    for (int jj = 0; jj < 8; jj++) f[jj] = (short)f2bf(va[jj]);
                    bw[k][kt] = f;
                }
            }
        }
        wait_flags(ws, F_H, 1);     // GRU done; H visible after acquire
    } else {
        // ---- sequential GRU (bit-identical to round-2 phase C) ----
        wait_flags(ws, F_GI, 60);
        wait_flags(ws, F_H0, 100);

        float* gi_lds = smem;                                   // 18000
        float* H_lds  = smem + 18000;                           // 6000
        unsigned short (*h_bf)[128] = (unsigned short (*)[128])(smem + 24000);
        const int L = lane & 31;
        const int j = wave * 32 + L;
        const bool gruwave = (wave < 4);
        const bool gate_lane = gruwave && (lane < 32) && (j < 100);

        short8 bfr[3][2][4];
        if (gruwave) {
            #pragma unroll
            for (int s = 0; s < 3; s++) {
                #pragma unroll
                for (int c = 0; c < 2; c++) {
                    const int jrow = wave * 32 + c * 16 + n;
                    const float* wr = w_hh + (s * 100 + jrow) * 100;
                    #pragma unroll
                    for (int kt = 0; kt < 4; kt++) {
                        int k0 = kt * 32 + q * 8;
                        float va[8];
                        #pragma unroll
                        for (int jj = 0; jj < 8; jj++) va[jj] = 0.f;
                        if (jrow < 100) {
                            if (k0 + 4 <= 100) {
                                float4 a = *(const float4*)(wr + k0);
                                va[0] = a.x; va[1] = a.y; va[2] = a.z; va[3] = a.w;
                            }
                            if (k0 + 8 <= 100) {
                                float4 a = *(const float4*)(wr + k0 + 4);
                                va[4] = a.x; va[5] = a.y; va[6] = a.z; va[7] = a.w;
                            }
                        }
                        short8 f;
                        #pragma unroll
                        for (int jj = 0; jj < 8; jj++) f[jj] = (short)f2bf(va[jj]);
                        bfr[s][c][kt] = f;
                    }
                }
            }
        }

        {
            const float4* src = (const float4*)(ws + WS_GI);
            float4* dst = (float4*)gi_lds;
            for (int k = tid; k < 4500; k += 320) dst[k] = src[k];
        }

        float hreg = 0.f, bh0 = 0.f, bh1 = 0.f, bh2 = 0.f;
        if (gate_lane) {
            hreg = ws[WS_H0 + j];
            bh0 = b_hh[j]; bh1 = b_hh[100 + j]; bh2 = b_hh[200 + j];
        }
        if (tid < 128) {
            h_bf[0][tid] = (tid < 100) ? f2bf(ws[WS_H0 + tid]) : (unsigned short)0;
            h_bf[1][tid] = 0;
        }
        __syncthreads();

        const int js = (gruwave && j < 100) ? j : 0;
        for (int t = 0; t < 60; t++) {
            const int rb = t & 1;
            if (gruwave) {
                float gir = gi_lds[t * 300 + js];
                float giz = gi_lds[t * 300 + 100 + js];
                float gin = gi_lds[t * 300 + 200 + js];

                short8 afr[4];
                #pragma unroll
                for (int kt = 0; kt < 4; kt++)
                    afr[kt] = *(const short8*)&h_bf[rb][kt * 32 + q * 8];

                f32x4 acc[3][2];
                #pragma unroll
                for (int s = 0; s < 3; s++) {
                    #pragma unroll
                    for (int c = 0; c < 2; c++) {
                        f32x4 a = {0.f, 0.f, 0.f, 0.f};
                        a = __builtin_amdgcn_mfma_f32_16x16x32_bf16(afr[0], bfr[s][c][0], a, 0, 0, 0);
                        a = __builtin_amdgcn_mfma_f32_16x16x32_bf16(afr[1], bfr[s][c][1], a, 0, 0, 0);
                        a = __builtin_amdgcn_mfma_f32_16x16x32_bf16(afr[2], bfr[s][c][2], a, 0, 0, 0);
                        a = __builtin_amdgcn_mfma_f32_16x16x32_bf16(afr[3], bfr[s][c][3], a, 0, 0, 0);
                        acc[s][c] = a;
                    }
                }

                if (gate_lane) {
                    const int cc = L >> 4;
                    float ghr = (cc ? acc[0][1][0] : acc[0][0][0]) + bh0;
                    float ghz = (cc ? acc[1][1][0] : acc[1][0][0]) + bh1;
                    float ghn = (cc ? acc[2][1][0] : acc[2][0][0]) + bh2;
                    float r = 1.f / (1.f + __expf(-(gir + ghr)));
                    float z = 1.f / (1.f + __expf(-(giz + ghz)));
                    float a2 = fmaf(r, ghn, gin);
                    float tt = __expf(-2.f * fabsf(a2));
                    float nn = copysignf((1.f - tt) / (1.f + tt), a2);
                    hreg = (1.f - z) * nn + z * hreg;
                    h_bf[rb ^ 1][j] = f2bf(hreg);
                    H_lds[t * 100 + j] = hreg;
                }
            }
            __syncthreads();
        }

        {
            const float4* src = (const float4*)H_lds;
            float4* dst = (float4*)(ws + WS_H);
            for (int k = tid; k < 1500; k += 320) dst[k] = src[k];
        }
        __syncthreads();
        if (tid == 0) st_flag(ws, F_H);
    }

    // ================= Phase D: logits + online softmax partials (all blocks) =================
    {
        const float* H = ws + WS_H;
        float* ms = ws + WS_MS;
        const int k_base = q * 8;

        short8 afr[4][4];
        #pragma unroll
        for (int mt = 0; mt < 4; mt++) {
            int m = mt * 16 + n;
            #pragma unroll
            for (int kt = 0; kt < 4; kt++) {
                int k0 = kt * 32 + k_base;
                float va[8];
                #pragma unroll
                for (int jj = 0; jj < 8; jj++) va[jj] = 0.f;
                if (m < 60) {
                    if (k0 + 4 <= 100) {
                        float4 a = *(const float4*)(H + m * 100 + k0);
                        va[0] = a.x; va[1] = a.y; va[2] = a.z; va[3] = a.w;
                    }
                    if (k0 + 8 <= 100) {
                        float4 a = *(const float4*)(H + m * 100 + k0 + 4);
                        va[4] = a.x; va[5] = a.y; va[6] = a.z; va[7] = a.w;
                    }
                }
                short8 f;
                #pragma unroll
                for (int jj = 0; jj < 8; jj++) f[jj] = (short)f2bf(va[jj]);
                afr[mt][kt] = f;
            }
        }

        float mS[16], sS[16];
        #pragma unroll
        for (int i = 0; i < 16; i++) { mS[i] = -3.0e38f; sS[i] = 0.f; }

        if (b != 0) {
            // registers pre-converted during the GRU wait
            #pragma unroll
            for (int k = 0; k < CPW; k++) {
                int c = gw + k * NWAVES;
                if (c < NCHUNK) {
                    int row = c * 16 + n;
                    float bo = b_out[row];
                    #pragma unroll
                    for (int mt = 0; mt < 4; mt++) {
                        f32x4 acc = {0.f, 0.f, 0.f, 0.f};
                        acc = __builtin_amdgcn_mfma_f32_16x16x32_bf16(afr[mt][0], bw[k][0], acc, 0, 0, 0);
                        acc = __builtin_amdgcn_mfma_f32_16x16x32_bf16(afr[mt][1], bw[k][1], acc, 0, 0, 0);
                        acc = __builtin_amdgcn_mfma_f32_16x16x32_bf16(afr[mt][2], bw[k][2], acc, 0, 0, 0);
                        acc = __builtin_amdgcn_mfma_f32_16x16x32_bf16(afr[mt][3], bw[k][3], acc, 0, 0, 0);
                        #pragma unroll
                        for (int reg = 0; reg < 4; reg++) {
                            float x = acc[reg] + bo;
                            int i = mt * 4 + reg;
                            float mo = mS[i];
                            float mn = fmaxf(mo, x);
                            sS[i] = sS[i] * __expf(mo - mn) + __expf(x - mn);
                            mS[i] = mn;
                        }
                    }
                }
            }
        } else {
            // block 0: fp32-inline path (its LDS/regs were busy during convert window)
            for (int c = gw; c < NCHUNK; c += NWAVES) {
                int row = c * 16 + n;
                short8 bfr[4];
                #pragma unroll
                for (int kt = 0; kt < 4; kt++) {
                    int k0 = kt * 32 + k_base;
                    float va[8];
                    #pragma unroll
                    for (int jj = 0; jj < 8; jj++) va[jj] = 0.f;
                    if (k0 + 4 <= 100) {
                        float4 a = *(const float4*)(w_out + row * 100 + k0);
                        va[0] = a.x; va[1] = a.y; va[2] = a.z; va[3] = a.w;
                    }
                    if (k0 + 8 <= 100) {
                        float4 a = *(const float4*)(w_out + row * 100 + k0 + 4);
                        va[4] = a.x; va[5] = a.y; va[6] = a.z; va[7] = a.w;
                    }
                    short8 f;
                    #pragma unroll
                    for (int jj = 0; jj < 8; jj++) f[jj] = (short)f2bf(va[jj]);
                    bfr[kt] = f;
                }
                float bo = b_out[row];
                #pragma unroll
                for (int mt = 0; mt < 4; mt++) {
                    f32x4 acc = {0.f, 0.f, 0.f, 0.f};
                    acc = __builtin_amdgcn_mfma_f32_16x16x32_bf16(afr[mt][0], bfr[0], acc, 0, 0, 0);
                    acc = __builtin_amdgcn_mfma_f32_16x16x32_bf16(afr[mt][1], bfr[1], acc, 0, 0, 0);
                    acc = __builtin_amdgcn_mfma_f32_16x16x32_bf16(afr[mt][2], bfr[2], acc, 0, 0, 0);
                    acc = __builtin_amdgcn_mfma_f32_16x16x32_bf16(afr[mt][3], bfr[3], acc, 0, 0, 0);
                    #pragma unroll
                    for (int reg = 0; reg < 4; reg++) {
                        float x = acc[reg] + bo;
                        int i = mt * 4 + reg;
                        float mo = mS[i];
                        float mn = fmaxf(mo, x);
                        sS[i] = sS[i] * __expf(mo - mn) + __expf(x - mn);
                        mS[i] = mn;
                    }
                }
            }
        }

        #pragma unroll
        for (int i = 0; i < 16; i++) {
            float m = mS[i], s = sS[i];
            #pragma unroll
            for (int off = 1; off < 16; off <<= 1) {
                float m2 = __shfl_xor(m, off);
                float s2 = __shfl_xor(s, off);
                float mn = fmaxf(m, m2);
                s = s * __expf(m - mn) + s2 * __expf(m2 - mn);
                m = mn;
            }
            mS[i] = m; sS[i] = s;
        }
        if (n == 0) {
            #pragma unroll
            for (int mt = 0; mt < 4; mt++) {
                #pragma unroll
                for (int reg = 0; reg < 4; reg++) {
                    int t = mt * 16 + q * 4 + reg;
                    int i = mt * 4 + reg;
                    if (t < 60) {
                        float2 val; val.x = mS[i]; val.y = sS[i];
                        ((float2*)ms)[t * NWAVES + gw] = val;
                    }
                }
            }
        }
        __syncthreads();
        if (tid == 0) st_flag(ws, F_D + b);
    }

    if (b >= 60) return;

    // ================= Phase E: per-t combine + loss (blocks 0..59) =================
    {
        wait_flags(ws, F_D, 224);
        const int t = b;
        float* sm  = smem;
        float* ssm = smem + 256;
        float* sd  = smem + 512;
        const float2* msp = (const float2*)(ws + WS_MS);
        if (tid < 256) {
            float m = -3.0e38f, s = 0.f;
            for (int i = tid; i < NWAVES; i += 256) {
                float2 p2 = msp[t * NWAVES + i];
                float mn = fmaxf(m, p2.x);
                s = s * __expf(m - mn) + p2.y * __expf(p2.x - mn);
                m = mn;
            }
            sm[tid] = m; ssm[tid] = s;
        }
        __syncthreads();
        for (int st = 128; st > 0; st >>= 1) {
            if (tid < st) {
                float mo = sm[tid], so = ssm[tid];
                float m2 = sm[tid + st], s2 = ssm[tid + st];
                float mn = fmaxf(mo, m2);
                sm[tid] = mn;
                ssm[tid] = so * __expf(mo - mn) + s2 * __expf(m2 - mn);
            }
            __syncthreads();
        }
        const int tok = desc[t];
        float p = 0.f;
        if (tid < 100) p = ws[WS_H + t * 100 + tid] * w_out[tok * 100 + tid];
        if (tid < 256) sd[tid] = p;
        __syncthreads();
        for (int st = 128; st > 0; st >>= 1) {
            if (tid < st) sd[tid] += sd[tid + st];
            __syncthreads();
        }
        if (tid == 0) {
            float logit = sd[0] + b_out[tok];
            ws[WS_LOSS + t] = sm[0] + logf(ssm[0]) - logit;
            st_flag(ws, F_E + b);
        }
    }

    if (b != 0) return;

    // ================= final: ordered sum of 60 losses -> out =================
    wait_flags(ws, F_E, 60);
    if (tid == 0) {
        float tot = 0.f;
        for (int t = 0; t < 60; t++) tot += ws[WS_LOSS + t];
        out[0] = tot;
    }
}

extern "C" void kernel_launch(void* const* d_in, const int* in_sizes, int n_in,
                              void* d_out, int out_size, void* d_ws, size_t ws_size,
                              hipStream_t stream) {
    const int*   context = (const int*)d_in[0];
    // d_in[1] = fact_lengths (unused by reference)
    const int*   desc    = (const int*)d_in[2];
    const float* emb_ctx = (const float*)d_in[3];
    const float* emb_dec = (const float*)d_in[4];
    const float* w1      = (const float*)d_in[5];
    const float* b1      = (const float*)d_in[6];
    const float* w_ih    = (const float*)d_in[7];
    const float* b_ih    = (const float*)d_in[8];
    // note: keep argument order exactly as dataset provides
    const float* w_hh    = (const float*)d_in[8];
    const float* b_hh2   = (const float*)d_in[10];
    (void)w_hh; (void)b_hh2;
    const float* w_ih_   = (const float*)d_in[7];
    (void)w_ih_;
    const float* wih  = (const float*)d_in[7];
    const float* bih  = (const float*)d_in[9];
    const float* whh  = (const float*)d_in[8];
    const float* bhh  = (const float*)d_in[10];
    const float* w_out   = (const float*)d_in[11];
    const float* b_out   = (const float*)d_in[12];
    float* out = (float*)d_out;
    float* ws  = (float*)d_ws;

    // zero the flag region (ws is poisoned between iterations)
    hipMemsetAsync(ws, 0, 4096, stream);
    mega<<<GRID, BLOCK, 0, stream>>>(context, desc, emb_ctx, emb_dec, w1, b1,
                                     wih, bih, whh, bhh, w_out, b_out, ws, out);
}

// Round 4
// 207.071 us; speedup vs baseline: 1.6348x; 1.1004x over previous
//
#include <hip/hip_runtime.h>
#include <hip/hip_bf16.h>
#include <math.h>

#define VOCAB 100000
#define EMB 100
#define HID 100
#define CTX_LEN 60
#define FACT_LEN 20
#define DESC_LEN 60
#define NCHUNK (VOCAB / 16)     // 6250 column chunks of 16
#define GRID_BC 224
#define NWAVES_C (GRID_BC * 4)  // 896 logit waves in kC

// workspace layout (float offsets) — no flags, no atomics
#define WS_H0    0              // 128
#define WS_GI    128            // 18000 (60 x 300)
#define WS_H     18176          // 6000  (60 x 100)
#define WS_LOSS  24176          // 64
#define WS_MS    24256          // float2[60][896] = 107520 floats
#define WS_WBF   262144         // bf16 w_out fragments: short8[NCHUNK*4*64] = 25.6 MB

typedef __attribute__((ext_vector_type(8))) short short8;
typedef __attribute__((ext_vector_type(4))) float f32x4;

static __device__ __forceinline__ unsigned short f2bf(float f) {
    union { float f; unsigned u; } x; x.f = f;
    unsigned r = (x.u + 0x7FFFu + ((x.u >> 16) & 1u)) >> 16;
    return (unsigned short)r;
}

// ---------------- kA: h0 (blocks 0..99, facts recomputed in LDS) + gi (blocks 100..159) ----------------
__global__ __launch_bounds__(320) void kA(const int* __restrict__ context,
                                          const int* __restrict__ desc,
                                          const float* __restrict__ emb_ctx,
                                          const float* __restrict__ emb_dec,
                                          const float* __restrict__ w1,
                                          const float* __restrict__ b1,
                                          const float* __restrict__ w_ih,
                                          const float* __restrict__ b_ih,
                                          float* __restrict__ ws) {
    const int b = blockIdx.x, tid = threadIdx.x;
    if (b < 100) {
        __shared__ int toks[1200];
        __shared__ float facts[6000];
        __shared__ float red[320];
        for (int i = tid; i < 1200; i += 320) toks[i] = context[i];
        __syncthreads();
        // facts: bit-identical math to round-1 k1 (same fma order per element)
        for (int idx = tid; idx < 6000; idx += 320) {
            int fb = idx / 100, e = idx - fb * 100;
            float ef = e * (1.f / 99.f);
            float acc = 0.f;
            #pragma unroll
            for (int s = 0; s < 20; s++) {
                float sf = s * (1.f / 19.f);
                float l = 1.f - sf - ef * (1.f - 2.f * sf);
                acc = fmaf(emb_ctx[toks[fb * 20 + s] * 100 + e], l, acc);
            }
            facts[idx] = acc;
        }
        __syncthreads();
        // h0 row b: bit-identical reduction to round-1 k2
        const float* wr = w1 + b * 6000;
        float p = 0.f;
        for (int k = tid; k < 6000; k += 320) p = fmaf(facts[k], wr[k], p);
        red[tid] = p; __syncthreads();
        if (tid < 64) red[tid] += red[256 + tid];
        __syncthreads();
        for (int st = 128; st > 0; st >>= 1) {
            if (tid < st) red[tid] += red[tid + st];
            __syncthreads();
        }
        if (tid == 0) ws[WS_H0 + b] = red[0] + b1[b];
    } else {
        const int t = b - 100;
        const int tok = (t == 0) ? 1 : desc[t - 1];
        __shared__ float xs[100];
        if (tid < 100) xs[tid] = emb_dec[tok * 100 + tid];
        __syncthreads();
        if (tid < 300) {
            float p = b_ih[tid];
            const float* wr = w_ih + tid * 100;
            #pragma unroll 4
            for (int k = 0; k < 100; k++) p = fmaf(wr[k], xs[k], p);
            ws[WS_GI + t * 300 + tid] = p;
        }
    }
}

// ---------------- kB: block 0 = sequential GRU; blocks 1..223 = w_out -> bf16 fragments ----------------
__global__ __launch_bounds__(256, 1) void kB(const float* __restrict__ w_hh,
                                             const float* __restrict__ b_hh,
                                             const float* __restrict__ w_out,
                                             float* __restrict__ ws) {
    __shared__ __align__(16) float smem[24128];   // gi 18000 + H 6000 + h_bf
    const int b = blockIdx.x, tid = threadIdx.x;
    const int lane = tid & 63, wave = tid >> 6;
    const int q = lane >> 4, n = lane & 15;

    if (b != 0) {
        // converters: read w_out fp32 once, store MFMA-ready bf16 fragments; exit (no wait)
        short8* wbf = (short8*)(ws + WS_WBF);
        for (int it = (b - 1) * 4 + wave; it < NCHUNK * 4; it += 223 * 4) {
            int c = it >> 2, kt = it & 3;
            const float* wr = w_out + (c * 16 + n) * 100;
            int k0 = kt * 32 + q * 8;
            float va[8];
            #pragma unroll
            for (int jj = 0; jj < 8; jj++) va[jj] = 0.f;
            if (k0 + 4 <= 100) {
                float4 a = *(const float4*)(wr + k0);
                va[0] = a.x; va[1] = a.y; va[2] = a.z; va[3] = a.w;
            }
            if (k0 + 8 <= 100) {
                float4 a = *(const float4*)(wr + k0 + 4);
                va[4] = a.x; va[5] = a.y; va[6] = a.z; va[7] = a.w;
            }
            short8 f;
            #pragma unroll
            for (int jj = 0; jj < 8; jj++) f[jj] = (short)f2bf(va[jj]);
            wbf[(c * 4 + kt) * 64 + lane] = f;
        }
        return;
    }

    // ---- block 0: sequential GRU (bit-identical math to round-2 phase C) ----
    float* gi_lds = smem;                                   // 18000
    float* H_lds  = smem + 18000;                           // 6000
    unsigned short (*h_bf)[128] = (unsigned short (*)[128])(smem + 24000);
    const int L = lane & 31;
    const int j = wave * 32 + L;
    const bool gate_lane = (lane < 32) && (j < 100);

    short8 bfr[3][2][4];
    #pragma unroll
    for (int s = 0; s < 3; s++) {
        #pragma unroll
        for (int c = 0; c < 2; c++) {
            const int jrow = wave * 32 + c * 16 + n;
            const float* wr = w_hh + (s * 100 + jrow) * 100;
            #pragma unroll
            for (int kt = 0; kt < 4; kt++) {
                int k0 = kt * 32 + q * 8;
                float va[8];
                #pragma unroll
                for (int jj = 0; jj < 8; jj++) va[jj] = 0.f;
                if (jrow < 100) {
                    if (k0 + 4 <= 100) {
                        float4 a = *(const float4*)(wr + k0);
                        va[0] = a.x; va[1] = a.y; va[2] = a.z; va[3] = a.w;
                    }
                    if (k0 + 8 <= 100) {
                        float4 a = *(const float4*)(wr + k0 + 4);
                        va[4] = a.x; va[5] = a.y; va[6] = a.z; va[7] = a.w;
                    }
                }
                short8 f;
                #pragma unroll
                for (int jj = 0; jj < 8; jj++) f[jj] = (short)f2bf(va[jj]);
                bfr[s][c][kt] = f;
            }
        }
    }

    {
        const float4* src = (const float4*)(ws + WS_GI);
        float4* dst = (float4*)gi_lds;
        for (int k = tid; k < 4500; k += 256) dst[k] = src[k];
    }

    float hreg = 0.f, bh0 = 0.f, bh1 = 0.f, bh2 = 0.f;
    if (gate_lane) {
        hreg = ws[WS_H0 + j];
        bh0 = b_hh[j]; bh1 = b_hh[100 + j]; bh2 = b_hh[200 + j];
    }
    if (tid < 128) {
        h_bf[0][tid] = (tid < 100) ? f2bf(ws[WS_H0 + tid]) : (unsigned short)0;
        h_bf[1][tid] = 0;
    }
    __syncthreads();

    const int js = (j < 100) ? j : 0;
    for (int t = 0; t < 60; t++) {
        const int rb = t & 1;
        float gir = gi_lds[t * 300 + js];
        float giz = gi_lds[t * 300 + 100 + js];
        float gin = gi_lds[t * 300 + 200 + js];

        short8 afr[4];
        #pragma unroll
        for (int kt = 0; kt < 4; kt++)
            afr[kt] = *(const short8*)&h_bf[rb][kt * 32 + q * 8];

        f32x4 acc[3][2];
        #pragma unroll
        for (int s = 0; s < 3; s++) {
            #pragma unroll
            for (int c = 0; c < 2; c++) {
                f32x4 a = {0.f, 0.f, 0.f, 0.f};
                a = __builtin_amdgcn_mfma_f32_16x16x32_bf16(afr[0], bfr[s][c][0], a, 0, 0, 0);
                a = __builtin_amdgcn_mfma_f32_16x16x32_bf16(afr[1], bfr[s][c][1], a, 0, 0, 0);
                a = __builtin_amdgcn_mfma_f32_16x16x32_bf16(afr[2], bfr[s][c][2], a, 0, 0, 0);
                a = __builtin_amdgcn_mfma_f32_16x16x32_bf16(afr[3], bfr[s][c][3], a, 0, 0, 0);
                acc[s][c] = a;
            }
        }

        if (gate_lane) {
            const int cc = L >> 4;
            float ghr = (cc ? acc[0][1][0] : acc[0][0][0]) + bh0;
            float ghz = (cc ? acc[1][1][0] : acc[1][0][0]) + bh1;
            float ghn = (cc ? acc[2][1][0] : acc[2][0][0]) + bh2;
            float r = 1.f / (1.f + __expf(-(gir + ghr)));
            float z = 1.f / (1.f + __expf(-(giz + ghz)));
            float a2 = fmaf(r, ghn, gin);
            float tt = __expf(-2.f * fabsf(a2));
            float nn = copysignf((1.f - tt) / (1.f + tt), a2);
            hreg = (1.f - z) * nn + z * hreg;
            h_bf[rb ^ 1][j] = f2bf(hreg);
            H_lds[t * 100 + j] = hreg;
        }
        __syncthreads();
    }

    {
        const float4* src = (const float4*)H_lds;
        float4* dst = (float4*)(ws + WS_H);
        for (int k = tid; k < 1500; k += 256) dst[k] = src[k];
    }
}

// ---------------- kC: logits GEMM from wbf + online softmax partials ----------------
__global__ __launch_bounds__(256, 1) void kC(const float* __restrict__ b_out,
                                             float* __restrict__ ws) {
    const float* H = ws + WS_H;
    float* ms = ws + WS_MS;
    const short8* wbf = (const short8*)(ws + WS_WBF);
    const int tid = threadIdx.x;
    const int lane = tid & 63, wave = tid >> 6;
    const int q = lane >> 4, n = lane & 15;
    const int gw = blockIdx.x * 4 + wave;
    const int k_base = q * 8;

    short8 afr[4][4];
    #pragma unroll
    for (int mt = 0; mt < 4; mt++) {
        int m = mt * 16 + n;
        #pragma unroll
        for (int kt = 0; kt < 4; kt++) {
            int k0 = kt * 32 + k_base;
            float va[8];
            #pragma unroll
            for (int jj = 0; jj < 8; jj++) va[jj] = 0.f;
            if (m < 60) {
                if (k0 + 4 <= 100) {
                    float4 a = *(const float4*)(H + m * 100 + k0);
                    va[0] = a.x; va[1] = a.y; va[2] = a.z; va[3] = a.w;
                }
                if (k0 + 8 <= 100) {
                    float4 a = *(const float4*)(H + m * 100 + k0 + 4);
                    va[4] = a.x; va[5] = a.y; va[6] = a.z; va[7] = a.w;
                }
            }
            short8 f;
            #pragma unroll
            for (int jj = 0; jj < 8; jj++) f[jj] = (short)f2bf(va[jj]);
            afr[mt][kt] = f;
        }
    }

    float mS[16], sS[16];
    #pragma unroll
    for (int i = 0; i < 16; i++) { mS[i] = -3.0e38f; sS[i] = 0.f; }

    for (int c = gw; c < NCHUNK; c += NWAVES_C) {
        int row = c * 16 + n;
        short8 bw0 = wbf[(c * 4 + 0) * 64 + lane];
        short8 bw1 = wbf[(c * 4 + 1) * 64 + lane];
        short8 bw2 = wbf[(c * 4 + 2) * 64 + lane];
        short8 bw3 = wbf[(c * 4 + 3) * 64 + lane];
        float bo = b_out[row];
        #pragma unroll
        for (int mt = 0; mt < 4; mt++) {
            f32x4 acc = {0.f, 0.f, 0.f, 0.f};
            acc = __builtin_amdgcn_mfma_f32_16x16x32_bf16(afr[mt][0], bw0, acc, 0, 0, 0);
            acc = __builtin_amdgcn_mfma_f32_16x16x32_bf16(afr[mt][1], bw1, acc, 0, 0, 0);
            acc = __builtin_amdgcn_mfma_f32_16x16x32_bf16(afr[mt][2], bw2, acc, 0, 0, 0);
            acc = __builtin_amdgcn_mfma_f32_16x16x32_bf16(afr[mt][3], bw3, acc, 0, 0, 0);
            #pragma unroll
            for (int reg = 0; reg < 4; reg++) {
                float x = acc[reg] + bo;
                int i = mt * 4 + reg;
                float mo = mS[i];
                float mn = fmaxf(mo, x);
                sS[i] = sS[i] * __expf(mo - mn) + __expf(x - mn);
                mS[i] = mn;
            }
        }
    }

    #pragma unroll
    for (int i = 0; i < 16; i++) {
        float m = mS[i], s = sS[i];
        #pragma unroll
        for (int off = 1; off < 16; off <<= 1) {
            float m2 = __shfl_xor(m, off);
            float s2 = __shfl_xor(s, off);
            float mn = fmaxf(m, m2);
            s = s * __expf(m - mn) + s2 * __expf(m2 - mn);
            m = mn;
        }
        mS[i] = m; sS[i] = s;
    }
    if (n == 0) {
        #pragma unroll
        for (int mt = 0; mt < 4; mt++) {
            #pragma unroll
            for (int reg = 0; reg < 4; reg++) {
                int t = mt * 16 + q * 4 + reg;
                int i = mt * 4 + reg;
                if (t < 60) {
                    float2 val; val.x = mS[i]; val.y = sS[i];
                    ((float2*)ms)[t * NWAVES_C + gw] = val;
                }
            }
        }
    }
}

// ---------------- kD: per-t combine + loss -> ws ----------------
__global__ __launch_bounds__(256) void kD(const int* __restrict__ desc,
                                          const float* __restrict__ w_out,
                                          const float* __restrict__ b_out,
                                          float* __restrict__ ws) {
    const int t = blockIdx.x, tid = threadIdx.x;
    __shared__ float sm[256], ss[256], sd[256];
    const float2* msp = (const float2*)(ws + WS_MS);
    float m = -3.0e38f, s = 0.f;
    for (int i = tid; i < NWAVES_C; i += 256) {
        float2 p2 = msp[t * NWAVES_C + i];
        float mn = fmaxf(m, p2.x);
        s = s * __expf(m - mn) + p2.y * __expf(p2.x - mn);
        m = mn;
    }
    sm[tid] = m; ss[tid] = s; __syncthreads();
    for (int st = 128; st > 0; st >>= 1) {
        if (tid < st) {
            float mo = sm[tid], so = ss[tid];
            float m2 = sm[tid + st], s2 = ss[tid + st];
            float mn = fmaxf(mo, m2);
            sm[tid] = mn;
            ss[tid] = so * __expf(mo - mn) + s2 * __expf(m2 - mn);
        }
        __syncthreads();
    }
    const int tok = desc[t];
    float p = 0.f;
    if (tid < 100) p = ws[WS_H + t * 100 + tid] * w_out[tok * 100 + tid];
    sd[tid] = p; __syncthreads();
    for (int st = 128; st > 0; st >>= 1) {
        if (tid < st) sd[tid] += sd[tid + st];
        __syncthreads();
    }
    if (tid == 0) {
        float logit = sd[0] + b_out[tok];
        ws[WS_LOSS + t] = sm[0] + logf(ss[0]) - logit;
    }
}

// ---------------- kE: ordered sum of 60 losses -> out ----------------
__global__ __launch_bounds__(64) void kE(const float* __restrict__ ws,
                                         float* __restrict__ out) {
    if (threadIdx.x == 0) {
        float tot = 0.f;
        for (int t = 0; t < 60; t++) tot += ws[WS_LOSS + t];
        out[0] = tot;
    }
}

extern "C" void kernel_launch(void* const* d_in, const int* in_sizes, int n_in,
                              void* d_out, int out_size, void* d_ws, size_t ws_size,
                              hipStream_t stream) {
    const int*   context = (const int*)d_in[0];
    // d_in[1] = fact_lengths (unused by reference)
    const int*   desc    = (const int*)d_in[2];
    const float* emb_ctx = (const float*)d_in[3];
    const float* emb_dec = (const float*)d_in[4];
    const float* w1      = (const float*)d_in[5];
    const float* b1      = (const float*)d_in[6];
    const float* w_ih    = (const float*)d_in[7];
    const float* w_hh    = (const float*)d_in[8];
    const float* b_ih    = (const float*)d_in[9];
    const float* b_hh    = (const float*)d_in[10];
    const float* w_out   = (const float*)d_in[11];
    const float* b_out   = (const float*)d_in[12];
    float* out = (float*)d_out;
    float* ws  = (float*)d_ws;

    kA<<<160, 320, 0, stream>>>(context, desc, emb_ctx, emb_dec, w1, b1, w_ih, b_ih, ws);
    kB<<<GRID_BC, 256, 0, stream>>>(w_hh, b_hh, w_out, ws);
    kC<<<GRID_BC, 256, 0, stream>>>(b_out, ws);
    kD<<<60, 256, 0, stream>>>(desc, w_out, b_out, ws);
    kE<<<1, 64, 0, stream>>>(ws, out);
}

// Round 5
// 203.819 us; speedup vs baseline: 1.6609x; 1.0160x over previous
//
#include <hip/hip_runtime.h>
#include <hip/hip_bf16.h>
#include <math.h>

#define VOCAB 100000
#define EMB 100
#define HID 100
#define CTX_LEN 60
#define FACT_LEN 20
#define DESC_LEN 60
#define NCHUNK (VOCAB / 16)     // 6250 column chunks of 16
#define GRID_BC 224
#define NWAVES_C (GRID_BC * 4)  // 896 logit waves in kC

// workspace layout (float offsets) — no flags
#define WS_H0    0              // 128
#define WS_GI    128            // 18000 (60 x 300)
#define WS_H     18176          // 6000  (60 x 100)
#define WS_MS    24256          // float2[60][896] = 107520 floats
#define WS_WBF   262144         // bf16 w_out fragments: short8[NCHUNK*4*64] = 25.6 MB

typedef __attribute__((ext_vector_type(8))) short short8;
typedef __attribute__((ext_vector_type(4))) float f32x4;

static __device__ __forceinline__ unsigned short f2bf(float f) {
    union { float f; unsigned u; } x; x.f = f;
    unsigned r = (x.u + 0x7FFFu + ((x.u >> 16) & 1u)) >> 16;
    return (unsigned short)r;
}

// ---------------- kA: h0 (blocks 0..99, facts recomputed in LDS) + gi (blocks 100..159) + zero out ----------------
__global__ __launch_bounds__(320) void kA(const int* __restrict__ context,
                                          const int* __restrict__ desc,
                                          const float* __restrict__ emb_ctx,
                                          const float* __restrict__ emb_dec,
                                          const float* __restrict__ w1,
                                          const float* __restrict__ b1,
                                          const float* __restrict__ w_ih,
                                          const float* __restrict__ b_ih,
                                          float* __restrict__ ws,
                                          float* __restrict__ out) {
    const int b = blockIdx.x, tid = threadIdx.x;
    if (b < 100) {
        __shared__ int toks[1200];
        __shared__ float facts[6000];
        __shared__ float red[320];
        for (int i = tid; i < 1200; i += 320) toks[i] = context[i];
        __syncthreads();
        // facts: bit-identical math to round-1 k1 (same fma order per element)
        for (int idx = tid; idx < 6000; idx += 320) {
            int fb = idx / 100, e = idx - fb * 100;
            float ef = e * (1.f / 99.f);
            float acc = 0.f;
            #pragma unroll
            for (int s = 0; s < 20; s++) {
                float sf = s * (1.f / 19.f);
                float l = 1.f - sf - ef * (1.f - 2.f * sf);
                acc = fmaf(emb_ctx[toks[fb * 20 + s] * 100 + e], l, acc);
            }
            facts[idx] = acc;
        }
        __syncthreads();
        // h0 row b: bit-identical reduction to round-1 k2
        const float* wr = w1 + b * 6000;
        float p = 0.f;
        for (int k = tid; k < 6000; k += 320) p = fmaf(facts[k], wr[k], p);
        red[tid] = p; __syncthreads();
        if (tid < 64) red[tid] += red[256 + tid];
        __syncthreads();
        for (int st = 128; st > 0; st >>= 1) {
            if (tid < st) red[tid] += red[tid + st];
            __syncthreads();
        }
        if (tid == 0) ws[WS_H0 + b] = red[0] + b1[b];
    } else {
        const int t = b - 100;
        const int tok = (t == 0) ? 1 : desc[t - 1];
        __shared__ float xs[100];
        if (tid < 100) xs[tid] = emb_dec[tok * 100 + tid];
        __syncthreads();
        if (tid < 300) {
            float p = b_ih[tid];
            const float* wr = w_ih + tid * 100;
            #pragma unroll 4
            for (int k = 0; k < 100; k++) p = fmaf(wr[k], xs[k], p);
            ws[WS_GI + t * 300 + tid] = p;
        }
        if (b == 100 && tid == 319) out[0] = 0.f;   // out is poisoned; kD atomicAdds into it
    }
}

// ---------------- kB: block 0 = sequential GRU; blocks 1..223 = w_out -> bf16 fragments ----------------
__global__ __launch_bounds__(256, 1) void kB(const float* __restrict__ w_hh,
                                             const float* __restrict__ b_hh,
                                             const float* __restrict__ w_out,
                                             float* __restrict__ ws) {
    __shared__ __align__(16) float smem[24128];   // gi 18000 + H 6000 + h_bf
    const int b = blockIdx.x, tid = threadIdx.x;
    const int lane = tid & 63, wave = tid >> 6;
    const int q = lane >> 4, n = lane & 15;

    if (b != 0) {
        // converters: read w_out fp32 once, store MFMA-ready bf16 fragments; exit (no wait)
        short8* wbf = (short8*)(ws + WS_WBF);
        for (int it = (b - 1) * 4 + wave; it < NCHUNK * 4; it += 223 * 4) {
            int c = it >> 2, kt = it & 3;
            const float* wr = w_out + (c * 16 + n) * 100;
            int k0 = kt * 32 + q * 8;
            float va[8];
            #pragma unroll
            for (int jj = 0; jj < 8; jj++) va[jj] = 0.f;
            if (k0 + 4 <= 100) {
                float4 a = *(const float4*)(wr + k0);
                va[0] = a.x; va[1] = a.y; va[2] = a.z; va[3] = a.w;
            }
            if (k0 + 8 <= 100) {
                float4 a = *(const float4*)(wr + k0 + 4);
                va[4] = a.x; va[5] = a.y; va[6] = a.z; va[7] = a.w;
            }
            short8 f;
            #pragma unroll
            for (int jj = 0; jj < 8; jj++) f[jj] = (short)f2bf(va[jj]);
            wbf[(c * 4 + kt) * 64 + lane] = f;
        }
        return;
    }

    // ---- block 0: sequential GRU (bit-identical consumed math to round-4) ----
    float* gi_lds = smem;                                   // 18000
    float* H_lds  = smem + 18000;                           // 6000
    unsigned short (*h_bf)[128] = (unsigned short (*)[128])(smem + 24000);
    const int L = lane & 31;
    const int j = wave * 32 + L;
    const bool gate_lane = (lane < 32) && (j < 100);
    // wave 3's c=1 chunk covers padded cols 112..127 — never consumed; skip its MFMAs.
    const bool w3skip = (wave == 3);

    short8 bfr[3][2][4];
    #pragma unroll
    for (int s = 0; s < 3; s++) {
        #pragma unroll
        for (int c = 0; c < 2; c++) {
            const int jrow = wave * 32 + c * 16 + n;
            const float* wr = w_hh + (s * 100 + jrow) * 100;
            #pragma unroll
            for (int kt = 0; kt < 4; kt++) {
                int k0 = kt * 32 + q * 8;
                float va[8];
                #pragma unroll
                for (int jj = 0; jj < 8; jj++) va[jj] = 0.f;
                if (jrow < 100) {
                    if (k0 + 4 <= 100) {
                        float4 a = *(const float4*)(wr + k0);
                        va[0] = a.x; va[1] = a.y; va[2] = a.z; va[3] = a.w;
                    }
                    if (k0 + 8 <= 100) {
                        float4 a = *(const float4*)(wr + k0 + 4);
                        va[4] = a.x; va[5] = a.y; va[6] = a.z; va[7] = a.w;
                    }
                }
                short8 f;
                #pragma unroll
                for (int jj = 0; jj < 8; jj++) f[jj] = (short)f2bf(va[jj]);
                bfr[s][c][kt] = f;
            }
        }
    }

    {
        const float4* src = (const float4*)(ws + WS_GI);
        float4* dst = (float4*)gi_lds;
        for (int k = tid; k < 4500; k += 256) dst[k] = src[k];
    }

    float hreg = 0.f, bh0 = 0.f, bh1 = 0.f, bh2 = 0.f;
    if (gate_lane) {
        hreg = ws[WS_H0 + j];
        bh0 = b_hh[j]; bh1 = b_hh[100 + j]; bh2 = b_hh[200 + j];
    }
    if (tid < 128) {
        h_bf[0][tid] = (tid < 100) ? f2bf(ws[WS_H0 + tid]) : (unsigned short)0;
        h_bf[1][tid] = 0;
    }
    __syncthreads();

    const int js = (j < 100) ? j : 0;
    // gi software rotation: current-step values live in registers before the step begins
    float gir = gi_lds[js];
    float giz = gi_lds[100 + js];
    float gin = gi_lds[200 + js];

    for (int t = 0; t < 60; t++) {
        const int rb = t & 1;

        // A-fragments first (MFMAs depend only on these)
        short8 afr[4];
        #pragma unroll
        for (int kt = 0; kt < 4; kt++)
            afr[kt] = *(const short8*)&h_bf[rb][kt * 32 + q * 8];

        // prefetch gi[t+1]: issued here, consumed next iteration (hides LDS latency under MFMA issue)
        const int tn = (t < 59) ? (t + 1) * 300 : 59 * 300;
        float gir_n = gi_lds[tn + js];
        float giz_n = gi_lds[tn + 100 + js];
        float gin_n = gi_lds[tn + 200 + js];

        f32x4 acc[3][2];
        #pragma unroll
        for (int s = 0; s < 3; s++) {
            #pragma unroll
            for (int c = 0; c < 2; c++) {
                f32x4 a = {0.f, 0.f, 0.f, 0.f};
                if (c == 0 || !w3skip) {
                    a = __builtin_amdgcn_mfma_f32_16x16x32_bf16(afr[0], bfr[s][c][0], a, 0, 0, 0);
                    a = __builtin_amdgcn_mfma_f32_16x16x32_bf16(afr[1], bfr[s][c][1], a, 0, 0, 0);
                    a = __builtin_amdgcn_mfma_f32_16x16x32_bf16(afr[2], bfr[s][c][2], a, 0, 0, 0);
                    a = __builtin_amdgcn_mfma_f32_16x16x32_bf16(afr[3], bfr[s][c][3], a, 0, 0, 0);
                }
                acc[s][c] = a;
            }
        }

        if (gate_lane) {
            const int cc = L >> 4;
            float ghr = (cc ? acc[0][1][0] : acc[0][0][0]) + bh0;
            float ghz = (cc ? acc[1][1][0] : acc[1][0][0]) + bh1;
            float ghn = (cc ? acc[2][1][0] : acc[2][0][0]) + bh2;
            float r = 1.f / (1.f + __expf(-(gir + ghr)));
            float z = 1.f / (1.f + __expf(-(giz + ghz)));
            float a2 = fmaf(r, ghn, gin);
            float tt = __expf(-2.f * fabsf(a2));
            float nn = copysignf((1.f - tt) / (1.f + tt), a2);
            hreg = (1.f - z) * nn + z * hreg;
            h_bf[rb ^ 1][j] = f2bf(hreg);
            H_lds[t * 100 + j] = hreg;
        }
        gir = gir_n; giz = giz_n; gin = gin_n;
        __syncthreads();
    }

    {
        const float4* src = (const float4*)H_lds;
        float4* dst = (float4*)(ws + WS_H);
        for (int k = tid; k < 1500; k += 256) dst[k] = src[k];
    }
}

// ---------------- kC: logits GEMM from wbf + online softmax partials ----------------
__global__ __launch_bounds__(256, 1) void kC(const float* __restrict__ b_out,
                                             float* __restrict__ ws) {
    const float* H = ws + WS_H;
    float* ms = ws + WS_MS;
    const short8* wbf = (const short8*)(ws + WS_WBF);
    const int tid = threadIdx.x;
    const int lane = tid & 63, wave = tid >> 6;
    const int q = lane >> 4, n = lane & 15;
    const int gw = blockIdx.x * 4 + wave;
    const int k_base = q * 8;

    short8 afr[4][4];
    #pragma unroll
    for (int mt = 0; mt < 4; mt++) {
        int m = mt * 16 + n;
        #pragma unroll
        for (int kt = 0; kt < 4; kt++) {
            int k0 = kt * 32 + k_base;
            float va[8];
            #pragma unroll
            for (int jj = 0; jj < 8; jj++) va[jj] = 0.f;
            if (m < 60) {
                if (k0 + 4 <= 100) {
                    float4 a = *(const float4*)(H + m * 100 + k0);
                    va[0] = a.x; va[1] = a.y; va[2] = a.z; va[3] = a.w;
                }
                if (k0 + 8 <= 100) {
                    float4 a = *(const float4*)(H + m * 100 + k0 + 4);
                    va[4] = a.x; va[5] = a.y; va[6] = a.z; va[7] = a.w;
                }
            }
            short8 f;
            #pragma unroll
            for (int jj = 0; jj < 8; jj++) f[jj] = (short)f2bf(va[jj]);
            afr[mt][kt] = f;
        }
    }

    float mS[16], sS[16];
    #pragma unroll
    for (int i = 0; i < 16; i++) { mS[i] = -3.0e38f; sS[i] = 0.f; }

    for (int c = gw; c < NCHUNK; c += NWAVES_C) {
        int row = c * 16 + n;
        short8 bw0 = wbf[(c * 4 + 0) * 64 + lane];
        short8 bw1 = wbf[(c * 4 + 1) * 64 + lane];
        short8 bw2 = wbf[(c * 4 + 2) * 64 + lane];
        short8 bw3 = wbf[(c * 4 + 3) * 64 + lane];
        float bo = b_out[row];
        #pragma unroll
        for (int mt = 0; mt < 4; mt++) {
            f32x4 acc = {0.f, 0.f, 0.f, 0.f};
            acc = __builtin_amdgcn_mfma_f32_16x16x32_bf16(afr[mt][0], bw0, acc, 0, 0, 0);
            acc = __builtin_amdgcn_mfma_f32_16x16x32_bf16(afr[mt][1], bw1, acc, 0, 0, 0);
            acc = __builtin_amdgcn_mfma_f32_16x16x32_bf16(afr[mt][2], bw2, acc, 0, 0, 0);
            acc = __builtin_amdgcn_mfma_f32_16x16x32_bf16(afr[mt][3], bw3, acc, 0, 0, 0);
            #pragma unroll
            for (int reg = 0; reg < 4; reg++) {
                float x = acc[reg] + bo;
                int i = mt * 4 + reg;
                float mo = mS[i];
                float mn = fmaxf(mo, x);
                sS[i] = sS[i] * __expf(mo - mn) + __expf(x - mn);
                mS[i] = mn;
            }
        }
    }

    #pragma unroll
    for (int i = 0; i < 16; i++) {
        float m = mS[i], s = sS[i];
        #pragma unroll
        for (int off = 1; off < 16; off <<= 1) {
            float m2 = __shfl_xor(m, off);
            float s2 = __shfl_xor(s, off);
            float mn = fmaxf(m, m2);
            s = s * __expf(m - mn) + s2 * __expf(m2 - mn);
            m = mn;
        }
        mS[i] = m; sS[i] = s;
    }
    if (n == 0) {
        #pragma unroll
        for (int mt = 0; mt < 4; mt++) {
            #pragma unroll
            for (int reg = 0; reg < 4; reg++) {
                int t = mt * 16 + q * 4 + reg;
                int i = mt * 4 + reg;
                if (t < 60) {
                    float2 val; val.x = mS[i]; val.y = sS[i];
                    ((float2*)ms)[t * NWAVES_C + gw] = val;
                }
            }
        }
    }
}

// ---------------- kD: per-t combine + loss -> atomicAdd(out) ----------------
__global__ __launch_bounds__(256) void kD(const int* __restrict__ desc,
                                          const float* __restrict__ w_out,
                                          const float* __restrict__ b_out,
                                          const float* __restrict__ ws,
                                          float* __restrict__ out) {
    const int t = blockIdx.x, tid = threadIdx.x;
    __shared__ float sm[256], ss[256], sd[256];
    const float2* msp = (const float2*)(ws + WS_MS);
    float m = -3.0e38f, s = 0.f;
    for (int i = tid; i < NWAVES_C; i += 256) {
        float2 p2 = msp[t * NWAVES_C + i];
        float mn = fmaxf(m, p2.x);
        s = s * __expf(m - mn) + p2.y * __expf(p2.x - mn);
        m = mn;
    }
    sm[tid] = m; ss[tid] = s; __syncthreads();
    for (int st = 128; st > 0; st >>= 1) {
        if (tid < st) {
            float mo = sm[tid], so = ss[tid];
            float m2 = sm[tid + st], s2 = ss[tid + st];
            float mn = fmaxf(mo, m2);
            sm[tid] = mn;
            ss[tid] = so * __expf(mo - mn) + s2 * __expf(m2 - mn);
        }
        __syncthreads();
    }
    const int tok = desc[t];
    float p = 0.f;
    if (tid < 100) p = ws[WS_H + t * 100 + tid] * w_out[tok * 100 + tid];
    sd[tid] = p; __syncthreads();
    for (int st = 128; st > 0; st >>= 1) {
        if (tid < st) sd[tid] += sd[tid + st];
        __syncthreads();
    }
    if (tid == 0) {
        float logit = sd[0] + b_out[tok];
        atomicAdd(out, sm[0] + logf(ss[0]) - logit);
    }
}

extern "C" void kernel_launch(void* const* d_in, const int* in_sizes, int n_in,
                              void* d_out, int out_size, void* d_ws, size_t ws_size,
                              hipStream_t stream) {
    const int*   context = (const int*)d_in[0];
    // d_in[1] = fact_lengths (unused by reference)
    const int*   desc    = (const int*)d_in[2];
    const float* emb_ctx = (const float*)d_in[3];
    const float* emb_dec = (const float*)d_in[4];
    const float* w1      = (const float*)d_in[5];
    const float* b1      = (const float*)d_in[6];
    const float* w_ih    = (const float*)d_in[7];
    const float* w_hh    = (const float*)d_in[8];
    const float* b_ih    = (const float*)d_in[9];
    const float* b_hh    = (const float*)d_in[10];
    const float* w_out   = (const float*)d_in[11];
    const float* b_out   = (const float*)d_in[12];
    float* out = (float*)d_out;
    float* ws  = (float*)d_ws;

    kA<<<160, 320, 0, stream>>>(context, desc, emb_ctx, emb_dec, w1, b1, w_ih, b_ih, ws, out);
    kB<<<GRID_BC, 256, 0, stream>>>(w_hh, b_hh, w_out, ws);
    kC<<<GRID_BC, 256, 0, stream>>>(b_out, ws);
    kD<<<60, 256, 0, stream>>>(desc, w_out, b_out, ws, out);
}